// Round 5
// baseline (607.510 us; speedup 1.0000x reference)
//
#include <hip/hip_runtime.h>
#include <hip/hip_bf16.h>

// B=16, T_EN=256, T_DE=256, D=512, UNITS=128
// tanh(x) = (1-e)/(1+e), e = exp(-2x) = Een*Ede where E = 2^(-(2/ln2)*att).
// nu*tanh = 2nu/(1+e) - nu ; the -nu term is constant over the softmax axis
// (encoder i) and cancels. Pairwise combine:
//   nv0/(1+e0)+nv1/(1+e1) = [nv0+nv1 + nv0*e1 + nv1*e0] * rcp((1+e0)(1+e1))
#define TANH_SCALE 2.8853900817779268f   // 2/ln(2)

// ---------------- K1: E = exp2(-TANH_SCALE * (X @ W)) ----------------------
// grid (128, 2) x 256 thr. BM=32, BN=128, BK=64, 4x4 micro-tile.
// X staged transposed+swizzled: xt[k][row ^ ((k>>2&7)<<2)] -> conflict-free
// scatter writes AND aligned b128 reads (2 broadcast addrs per wave).
__global__ __launch_bounds__(256) void proj_kernel(
        const float* __restrict__ en, const float* __restrict__ de,
        const float* __restrict__ w_en, const float* __restrict__ w_de,
        float* __restrict__ Een, float* __restrict__ Ede) {
    const float* X;
    const float* W;
    float* OUT;
    if (blockIdx.y == 0) { X = en; W = w_en; OUT = Een; }
    else                 { X = de; W = w_de; OUT = Ede; }

    __shared__ float xt[64][36];     // [k][row(swizzled)], 9 KB
    __shared__ float wsh[64][128];   // 32 KB
    const int tid  = threadIdx.x;
    const int tr   = tid >> 5;       // 0..7  -> rows tr*4..+3
    const int tc   = tid & 31;       // cols tc*4..+3
    const int row0 = blockIdx.x * 32;

    // staging maps (per thread): X: 2 float4, W: 8 float4
    const int xs_r  = tid >> 4;            // 0..15 (+16 for s=1)
    const int xs_k4 = (tid & 15) * 4;      // 0..60
    float4 xr[2], wr[8];

    auto g_load = [&](int kt) {
#pragma unroll
        for (int s = 0; s < 2; ++s) {
            int r = xs_r + 16 * s;
            xr[s] = *reinterpret_cast<const float4*>(
                X + (size_t)(row0 + r) * 512 + kt + xs_k4);
        }
#pragma unroll
        for (int s = 0; s < 8; ++s) {
            int idx = tid + 256 * s;
            int k = idx >> 5, c4 = (idx & 31) * 4;
            wr[s] = *reinterpret_cast<const float4*>(
                W + (size_t)(kt + k) * 128 + c4);
        }
    };
    auto lds_store = [&]() {
        const int swz = ((xs_k4 >> 2) & 7) << 2;
#pragma unroll
        for (int s = 0; s < 2; ++s) {
            int r = (xs_r + 16 * s) ^ swz;
            xt[xs_k4 + 0][r] = xr[s].x;
            xt[xs_k4 + 1][r] = xr[s].y;
            xt[xs_k4 + 2][r] = xr[s].z;
            xt[xs_k4 + 3][r] = xr[s].w;
        }
#pragma unroll
        for (int s = 0; s < 8; ++s) {
            int idx = tid + 256 * s;
            int k = idx >> 5, c4 = (idx & 31) * 4;
            *reinterpret_cast<float4*>(&wsh[k][c4]) = wr[s];
        }
    };

    float acc[4][4] = {{0.f}};
    g_load(0);
    lds_store();
    __syncthreads();

    for (int kt = 0; kt < 512; kt += 64) {
        const bool has_next = (kt + 64) < 512;
        if (has_next) g_load(kt + 64);    // issue early; hides under compute
#pragma unroll
        for (int k = 0; k < 64; ++k) {
            const int col = (tr * 4) ^ (((k >> 2) & 7) << 2);
            float4 xv = *reinterpret_cast<const float4*>(&xt[k][col]);
            float4 wv = *reinterpret_cast<const float4*>(&wsh[k][tc * 4]);
            acc[0][0] = fmaf(xv.x, wv.x, acc[0][0]);
            acc[0][1] = fmaf(xv.x, wv.y, acc[0][1]);
            acc[0][2] = fmaf(xv.x, wv.z, acc[0][2]);
            acc[0][3] = fmaf(xv.x, wv.w, acc[0][3]);
            acc[1][0] = fmaf(xv.y, wv.x, acc[1][0]);
            acc[1][1] = fmaf(xv.y, wv.y, acc[1][1]);
            acc[1][2] = fmaf(xv.y, wv.z, acc[1][2]);
            acc[1][3] = fmaf(xv.y, wv.w, acc[1][3]);
            acc[2][0] = fmaf(xv.z, wv.x, acc[2][0]);
            acc[2][1] = fmaf(xv.z, wv.y, acc[2][1]);
            acc[2][2] = fmaf(xv.z, wv.z, acc[2][2]);
            acc[2][3] = fmaf(xv.z, wv.w, acc[2][3]);
            acc[3][0] = fmaf(xv.w, wv.x, acc[3][0]);
            acc[3][1] = fmaf(xv.w, wv.y, acc[3][1]);
            acc[3][2] = fmaf(xv.w, wv.z, acc[3][2]);
            acc[3][3] = fmaf(xv.w, wv.w, acc[3][3]);
        }
        __syncthreads();
        if (has_next) {
            lds_store();
            __syncthreads();
        }
    }

#pragma unroll
    for (int r = 0; r < 4; ++r) {
        float4 o;
        o.x = __builtin_exp2f(-TANH_SCALE * acc[r][0]);
        o.y = __builtin_exp2f(-TANH_SCALE * acc[r][1]);
        o.z = __builtin_exp2f(-TANH_SCALE * acc[r][2]);
        o.w = __builtin_exp2f(-TANH_SCALE * acc[r][3]);
        *reinterpret_cast<float4*>(
            OUT + (size_t)(row0 + tr * 4 + r) * 128 + tc * 4) = o;
    }
}

// ---------------- K2: fused mu + softmax + PV + de-copy ---------------------
// 512 blocks x 512 threads. Block = (b, j-tile of 8 decoder rows).
// Phase A/B: i = tid&255, uh = tid>>8 handles j = uh*4..uh*4+3.
// Phase C: thread owns output column c = tid (0..511).
__global__ __launch_bounds__(512, 4) void fused_attn_kernel(
        const float* __restrict__ Een, const float* __restrict__ Ede,
        const float* __restrict__ nu, const float* __restrict__ en,
        const float* __restrict__ de, float* __restrict__ out) {
    const int phys = blockIdx.x;
    const int lid  = (phys & 7) * 64 + (phys >> 3);   // XCD swizzle (512%8==0)
    const int b    = lid >> 5;          // 0..15
    const int j0   = (lid & 31) * 8;    // 0..248
    const int tid  = threadIdx.x;
    const int i    = tid & 255;
    const int uh   = tid >> 8;          // 0/1

    __shared__ float ede_sh[8][128];    // 4 KB
    __shared__ float nu2_sh[128];       // 2*nu
    __shared__ float nusum_sh[64];      // 2*(nu[2t]+nu[2t+1])
    __shared__ float al[8][256];        // 8 KB alphas
    __shared__ float red[8][4];

    if (tid < 256)
        reinterpret_cast<float4*>(&ede_sh[0][0])[tid] =
            reinterpret_cast<const float4*>(Ede + ((size_t)b * 256 + j0) * 128)[tid];
    if (tid >= 256 && tid < 384) nu2_sh[tid - 256] = 2.0f * nu[tid - 256];
    if (tid >= 384 && tid < 448) {
        int t = tid - 384;
        nusum_sh[t] = 2.0f * (nu[2 * t] + nu[2 * t + 1]);
    }

    // de_seq copy into left half of out (overlaps everything)
    {
        const float4* dsrc =
            reinterpret_cast<const float4*>(de + ((size_t)b * 256 + j0) * 512);
#pragma unroll
        for (int t = 0; t < 2; ++t) {
            int idx = tid + 512 * t;        // 0..1023
            int j = idx >> 7, c4 = idx & 127;
            reinterpret_cast<float4*>(out + (size_t)(b * 256 + j0 + j) * 1024)[c4] =
                dsrc[idx];
        }
    }
    __syncthreads();

    // ---- phase A: s[jl] = sum_u nu2[u] / (1 + Een[i][u]*Ede[j][u]) ----
    float s[4] = {0.0f, 0.0f, 0.0f, 0.0f};
    const float4* e4 =
        reinterpret_cast<const float4*>(Een + ((size_t)b * 256 + i) * 128);
#pragma unroll
    for (int q = 0; q < 8; ++q) {       // chunks of 16 u = 8 pairs
        float ev[16], nv[16], cs[8];
#pragma unroll
        for (int t = 0; t < 4; ++t) {
            float4 a = e4[q * 4 + t];
            ev[4 * t] = a.x; ev[4 * t + 1] = a.y; ev[4 * t + 2] = a.z; ev[4 * t + 3] = a.w;
            float4 n = *reinterpret_cast<const float4*>(&nu2_sh[q * 16 + 4 * t]);
            nv[4 * t] = n.x; nv[4 * t + 1] = n.y; nv[4 * t + 2] = n.z; nv[4 * t + 3] = n.w;
        }
#pragma unroll
        for (int t2 = 0; t2 < 8; ++t2) cs[t2] = nusum_sh[q * 8 + t2];
#pragma unroll
        for (int jl = 0; jl < 4; ++jl) {
            const int j = uh * 4 + jl;
            float dv[16];
#pragma unroll
            for (int t = 0; t < 4; ++t) {
                float4 d = *reinterpret_cast<const float4*>(&ede_sh[j][q * 16 + 4 * t]);
                dv[4 * t] = d.x; dv[4 * t + 1] = d.y; dv[4 * t + 2] = d.z; dv[4 * t + 3] = d.w;
            }
#pragma unroll
            for (int t2 = 0; t2 < 8; ++t2) {
                float e0 = ev[2 * t2]     * dv[2 * t2];
                float e1 = ev[2 * t2 + 1] * dv[2 * t2 + 1];
                float den = 1.0f + e0;
                den = fmaf(den, e1, den);                 // (1+e0)(1+e1)
                float num = fmaf(nv[2 * t2], e1, cs[t2]);
                num = fmaf(nv[2 * t2 + 1], e0, num);
                s[jl] = fmaf(num, __builtin_amdgcn_rcpf(den), s[jl]);
            }
        }
    }

    // ---- phase B: softmax over i (shift by Sum(nu) cancels; exp is safe) ----
    float p[4];
#pragma unroll
    for (int jl = 0; jl < 4; ++jl) p[jl] = __expf(s[jl]);
    const int lane = tid & 63;
    const int w    = (tid >> 6) & 3;    // wave within half
#pragma unroll
    for (int jl = 0; jl < 4; ++jl) {
        float t = p[jl];
#pragma unroll
        for (int off = 32; off >= 1; off >>= 1) t += __shfl_xor(t, off);
        if (lane == 0) red[uh * 4 + jl][w] = t;
    }
    __syncthreads();
#pragma unroll
    for (int jl = 0; jl < 4; ++jl) {
        const int j = uh * 4 + jl;
        float T = red[j][0] + red[j][1] + red[j][2] + red[j][3];
        al[j][i] = p[jl] * __builtin_amdgcn_rcpf(T);
    }
    __syncthreads();

    // ---- phase C: sum_en[j][c] = sum_i al[j][i] * en[b][i][c], c = tid ----
    float acc[8];
#pragma unroll
    for (int j = 0; j < 8; ++j) acc[j] = 0.0f;
    const float* enb = en + (size_t)b * 256 * 512;
    const int c = tid;
    for (int i0 = 0; i0 < 256; i0 += 4) {
        float a[8][4];
#pragma unroll
        for (int j = 0; j < 8; ++j) {
            float4 v = *reinterpret_cast<const float4*>(&al[j][i0]);  // broadcast
            a[j][0] = v.x; a[j][1] = v.y; a[j][2] = v.z; a[j][3] = v.w;
        }
#pragma unroll
        for (int ii = 0; ii < 4; ++ii) {
            float e0 = enb[(size_t)(i0 + ii) * 512 + c];
#pragma unroll
            for (int j = 0; j < 8; ++j)
                acc[j] = fmaf(a[j][ii], e0, acc[j]);
        }
    }
#pragma unroll
    for (int j = 0; j < 8; ++j) {
        size_t row = (size_t)(b * 256 + j0 + j);
        out[row * 1024 + 512 + c] = acc[j];
    }
}

extern "C" void kernel_launch(void* const* d_in, const int* in_sizes, int n_in,
                              void* d_out, int out_size, void* d_ws, size_t ws_size,
                              hipStream_t stream) {
    const float* en   = (const float*)d_in[0];  // (16,256,512)
    const float* de   = (const float*)d_in[1];  // (16,256,512)
    const float* w_en = (const float*)d_in[2];  // (512,128)
    const float* w_de = (const float*)d_in[3];  // (512,128)
    const float* nu   = (const float*)d_in[4];  // (128,1)
    float* out = (float*)d_out;                 // (16,256,1024)

    char* ws = (char*)d_ws;
    float* Een = (float*)(ws);                          // 4096x128  2^(-s*att_en)
    float* Ede = (float*)(ws + (size_t)4096 * 128 * 4); // 4096x128  2^(-s*att_de)

    proj_kernel<<<dim3(128, 2), 256, 0, stream>>>(en, de, w_en, w_de, Een, Ede);
    fused_attn_kernel<<<dim3(512), 512, 0, stream>>>(Een, Ede, nu, en, de, out);
}

// Round 7
// 160.921 us; speedup vs baseline: 3.7752x; 3.7752x over previous
//
#include <hip/hip_runtime.h>
#include <hip/hip_bf16.h>

// B=16, T_EN=256, T_DE=256, D=512, UNITS=128
// tanh(x) = (1-e)/(1+e), e = exp(-2x) = Een*Ede where E = 2^(-(2/ln2)*att).
// nu*tanh = 2nu/(1+e) - nu ; the -nu term is constant over the softmax axis
// (encoder i) and cancels. Pairwise combine (one rcp per TWO u-terms):
//   nv0/(1+e0)+nv1/(1+e1) = [nv0+nv1 + nv0*e1 + nv1*e0] * rcp((1+e0)(1+e1))
#define TANH_SCALE 2.8853900817779268f   // 2/ln(2)

// ---------------- K1: E = exp2(-TANH_SCALE * (X @ W)) ----------------------
// grid (128, 2) x 256 thr. BM=32, BN=128, BK=64, 4x4 micro-tile.
// X staged transposed+swizzled: xt[k][row ^ ((k>>2&7)<<2)] -> conflict-free
// scatter writes AND aligned b128 reads.
__global__ __launch_bounds__(256) void proj_kernel(
        const float* __restrict__ en, const float* __restrict__ de,
        const float* __restrict__ w_en, const float* __restrict__ w_de,
        float* __restrict__ Een, float* __restrict__ Ede) {
    const float* X;
    const float* W;
    float* OUT;
    if (blockIdx.y == 0) { X = en; W = w_en; OUT = Een; }
    else                 { X = de; W = w_de; OUT = Ede; }

    __shared__ float xt[64][36];     // [k][row(swizzled)], 9 KB
    __shared__ float wsh[64][128];   // 32 KB
    const int tid  = threadIdx.x;
    const int tr   = tid >> 5;       // 0..7  -> rows tr*4..+3
    const int tc   = tid & 31;       // cols tc*4..+3
    const int row0 = blockIdx.x * 32;

    const int xs_r  = tid >> 4;            // 0..15 (+16 for s=1)
    const int xs_k4 = (tid & 15) * 4;      // 0..60
    float4 xr[2], wr[8];

    auto g_load = [&](int kt) {
#pragma unroll
        for (int s = 0; s < 2; ++s) {
            int r = xs_r + 16 * s;
            xr[s] = *reinterpret_cast<const float4*>(
                X + (size_t)(row0 + r) * 512 + kt + xs_k4);
        }
#pragma unroll
        for (int s = 0; s < 8; ++s) {
            int idx = tid + 256 * s;
            int k = idx >> 5, c4 = (idx & 31) * 4;
            wr[s] = *reinterpret_cast<const float4*>(
                W + (size_t)(kt + k) * 128 + c4);
        }
    };
    auto lds_store = [&]() {
        const int swz = ((xs_k4 >> 2) & 7) << 2;
#pragma unroll
        for (int s = 0; s < 2; ++s) {
            int r = (xs_r + 16 * s) ^ swz;
            xt[xs_k4 + 0][r] = xr[s].x;
            xt[xs_k4 + 1][r] = xr[s].y;
            xt[xs_k4 + 2][r] = xr[s].z;
            xt[xs_k4 + 3][r] = xr[s].w;
        }
#pragma unroll
        for (int s = 0; s < 8; ++s) {
            int idx = tid + 256 * s;
            int k = idx >> 5, c4 = (idx & 31) * 4;
            *reinterpret_cast<float4*>(&wsh[k][c4]) = wr[s];
        }
    };

    float acc[4][4] = {{0.f}};
    g_load(0);
    lds_store();
    __syncthreads();

    for (int kt = 0; kt < 512; kt += 64) {
        const bool has_next = (kt + 64) < 512;
        if (has_next) g_load(kt + 64);    // issue early; hides under compute
#pragma unroll
        for (int k = 0; k < 64; ++k) {
            const int col = (tr * 4) ^ (((k >> 2) & 7) << 2);
            float4 xv = *reinterpret_cast<const float4*>(&xt[k][col]);
            float4 wv = *reinterpret_cast<const float4*>(&wsh[k][tc * 4]);
            acc[0][0] = fmaf(xv.x, wv.x, acc[0][0]);
            acc[0][1] = fmaf(xv.x, wv.y, acc[0][1]);
            acc[0][2] = fmaf(xv.x, wv.z, acc[0][2]);
            acc[0][3] = fmaf(xv.x, wv.w, acc[0][3]);
            acc[1][0] = fmaf(xv.y, wv.x, acc[1][0]);
            acc[1][1] = fmaf(xv.y, wv.y, acc[1][1]);
            acc[1][2] = fmaf(xv.y, wv.z, acc[1][2]);
            acc[1][3] = fmaf(xv.y, wv.w, acc[1][3]);
            acc[2][0] = fmaf(xv.z, wv.x, acc[2][0]);
            acc[2][1] = fmaf(xv.z, wv.y, acc[2][1]);
            acc[2][2] = fmaf(xv.z, wv.z, acc[2][2]);
            acc[2][3] = fmaf(xv.z, wv.w, acc[2][3]);
            acc[3][0] = fmaf(xv.w, wv.x, acc[3][0]);
            acc[3][1] = fmaf(xv.w, wv.y, acc[3][1]);
            acc[3][2] = fmaf(xv.w, wv.z, acc[3][2]);
            acc[3][3] = fmaf(xv.w, wv.w, acc[3][3]);
        }
        __syncthreads();
        if (has_next) {
            lds_store();
            __syncthreads();
        }
    }

#pragma unroll
    for (int r = 0; r < 4; ++r) {
        float4 o;
        o.x = __builtin_exp2f(-TANH_SCALE * acc[r][0]);
        o.y = __builtin_exp2f(-TANH_SCALE * acc[r][1]);
        o.z = __builtin_exp2f(-TANH_SCALE * acc[r][2]);
        o.w = __builtin_exp2f(-TANH_SCALE * acc[r][3]);
        *reinterpret_cast<float4*>(
            OUT + (size_t)(row0 + tr * 4 + r) * 128 + tc * 4) = o;
    }
}

// ---------------- K2: fused mu + softmax + PV + de-copy ---------------------
// 512 blocks x 512 threads. Block = (b, j-tile of 8 decoder rows).
// Phase A/B: i = tid&255, uh = tid>>8 handles j = uh*4..uh*4+3.
// Phase C: thread owns output column c = tid (0..511).
// Register-light phase A: u chunked by 8 (4 pairs), no outer unroll ->
// live set ~40 VGPRs (round-5 lesson: 16-chunk + unroll spilled to scratch,
// 1.5 GB HBM traffic, 6x regression).
__global__ __launch_bounds__(512, 4) void fused_attn_kernel(
        const float* __restrict__ Een, const float* __restrict__ Ede,
        const float* __restrict__ nu, const float* __restrict__ en,
        const float* __restrict__ de, float* __restrict__ out) {
    const int phys = blockIdx.x;
    const int lid  = (phys & 7) * 64 + (phys >> 3);   // XCD swizzle (512%8==0)
    const int b    = lid >> 5;          // 0..15
    const int j0   = (lid & 31) * 8;    // 0..248
    const int tid  = threadIdx.x;
    const int i    = tid & 255;
    const int uh   = tid >> 8;          // 0/1

    __shared__ float ede_sh[8][128];    // 4 KB
    __shared__ float nu2_sh[128];       // 2*nu
    __shared__ float nusum_sh[64];      // 2*(nu[2p]+nu[2p+1]), float4-aligned
    __shared__ float al[8][256];        // 8 KB alphas
    __shared__ float red[8][4];

    if (tid < 256)
        reinterpret_cast<float4*>(&ede_sh[0][0])[tid] =
            reinterpret_cast<const float4*>(Ede + ((size_t)b * 256 + j0) * 128)[tid];
    if (tid >= 256 && tid < 384) nu2_sh[tid - 256] = 2.0f * nu[tid - 256];
    if (tid >= 384 && tid < 448) {
        int t = tid - 384;
        nusum_sh[t] = 2.0f * (nu[2 * t] + nu[2 * t + 1]);
    }

    // de_seq copy into left half of out (overlaps everything)
    {
        const float4* dsrc =
            reinterpret_cast<const float4*>(de + ((size_t)b * 256 + j0) * 512);
#pragma unroll
        for (int t = 0; t < 2; ++t) {
            int idx = tid + 512 * t;        // 0..1023
            int j = idx >> 7, c4 = idx & 127;
            reinterpret_cast<float4*>(out + (size_t)(b * 256 + j0 + j) * 1024)[c4] =
                dsrc[idx];
        }
    }
    __syncthreads();

    // ---- phase A: s[jl] = sum_u nu2[u] / (1 + Een[i][u]*Ede[j][u]) ----
    float s[4] = {0.0f, 0.0f, 0.0f, 0.0f};
    const float4* e4 =
        reinterpret_cast<const float4*>(Een + ((size_t)b * 256 + i) * 128);
    const float4* nu4 = reinterpret_cast<const float4*>(nu2_sh);
    const float4* cs4 = reinterpret_cast<const float4*>(nusum_sh);
    for (int q = 0; q < 16; ++q) {      // chunks of 8 u = 4 pairs; NOT unrolled
        const float4 ea = e4[2 * q];
        const float4 eb = e4[2 * q + 1];
        const float4 na = nu4[2 * q];
        const float4 nb = nu4[2 * q + 1];
        const float4 cs = cs4[q];
#pragma unroll
        for (int jl = 0; jl < 4; ++jl) {
            const float* dr = &ede_sh[uh * 4 + jl][8 * q];
            const float4 da = *reinterpret_cast<const float4*>(dr);
            const float4 db = *reinterpret_cast<const float4*>(dr + 4);
            float e0, e1, den, num;
            e0 = ea.x * da.x; e1 = ea.y * da.y;
            den = 1.0f + e0; den = fmaf(den, e1, den);
            num = fmaf(na.x, e1, cs.x); num = fmaf(na.y, e0, num);
            s[jl] = fmaf(num, __builtin_amdgcn_rcpf(den), s[jl]);
            e0 = ea.z * da.z; e1 = ea.w * da.w;
            den = 1.0f + e0; den = fmaf(den, e1, den);
            num = fmaf(na.z, e1, cs.y); num = fmaf(na.w, e0, num);
            s[jl] = fmaf(num, __builtin_amdgcn_rcpf(den), s[jl]);
            e0 = eb.x * db.x; e1 = eb.y * db.y;
            den = 1.0f + e0; den = fmaf(den, e1, den);
            num = fmaf(nb.x, e1, cs.z); num = fmaf(nb.y, e0, num);
            s[jl] = fmaf(num, __builtin_amdgcn_rcpf(den), s[jl]);
            e0 = eb.z * db.z; e1 = eb.w * db.w;
            den = 1.0f + e0; den = fmaf(den, e1, den);
            num = fmaf(nb.z, e1, cs.w); num = fmaf(nb.w, e0, num);
            s[jl] = fmaf(num, __builtin_amdgcn_rcpf(den), s[jl]);
        }
    }

    // ---- phase B: softmax over i (shift by Sum(nu) cancels; exp is safe) ----
    float p[4];
#pragma unroll
    for (int jl = 0; jl < 4; ++jl) p[jl] = __expf(s[jl]);
    const int lane = tid & 63;
    const int w    = (tid >> 6) & 3;    // wave within half
#pragma unroll
    for (int jl = 0; jl < 4; ++jl) {
        float t = p[jl];
#pragma unroll
        for (int off = 32; off >= 1; off >>= 1) t += __shfl_xor(t, off);
        if (lane == 0) red[uh * 4 + jl][w] = t;
    }
    __syncthreads();
#pragma unroll
    for (int jl = 0; jl < 4; ++jl) {
        const int j = uh * 4 + jl;
        float T = red[j][0] + red[j][1] + red[j][2] + red[j][3];
        al[j][i] = p[jl] * __builtin_amdgcn_rcpf(T);
    }
    __syncthreads();

    // ---- phase C: sum_en[j][c] = sum_i al[j][i] * en[b][i][c], c = tid ----
    float acc[8];
#pragma unroll
    for (int j = 0; j < 8; ++j) acc[j] = 0.0f;
    const float* enb = en + (size_t)b * 256 * 512;
    const int c = tid;
    for (int i0 = 0; i0 < 256; i0 += 4) {
        float a[8][4];
#pragma unroll
        for (int j = 0; j < 8; ++j) {
            float4 v = *reinterpret_cast<const float4*>(&al[j][i0]);  // broadcast
            a[j][0] = v.x; a[j][1] = v.y; a[j][2] = v.z; a[j][3] = v.w;
        }
#pragma unroll
        for (int ii = 0; ii < 4; ++ii) {
            float e0 = enb[(size_t)(i0 + ii) * 512 + c];
#pragma unroll
            for (int j = 0; j < 8; ++j)
                acc[j] = fmaf(a[j][ii], e0, acc[j]);
        }
    }
#pragma unroll
    for (int j = 0; j < 8; ++j) {
        size_t row = (size_t)(b * 256 + j0 + j);
        out[row * 1024 + 512 + c] = acc[j];
    }
}

extern "C" void kernel_launch(void* const* d_in, const int* in_sizes, int n_in,
                              void* d_out, int out_size, void* d_ws, size_t ws_size,
                              hipStream_t stream) {
    const float* en   = (const float*)d_in[0];  // (16,256,512)
    const float* de   = (const float*)d_in[1];  // (16,256,512)
    const float* w_en = (const float*)d_in[2];  // (512,128)
    const float* w_de = (const float*)d_in[3];  // (512,128)
    const float* nu   = (const float*)d_in[4];  // (128,1)
    float* out = (float*)d_out;                 // (16,256,1024)

    char* ws = (char*)d_ws;
    float* Een = (float*)(ws);                          // 4096x128  2^(-s*att_en)
    float* Ede = (float*)(ws + (size_t)4096 * 128 * 4); // 4096x128  2^(-s*att_de)

    proj_kernel<<<dim3(128, 2), 256, 0, stream>>>(en, de, w_en, w_de, Een, Ede);
    fused_attn_kernel<<<dim3(512), 512, 0, stream>>>(Een, Ede, nu, en, de, out);
}